// Round 2
// baseline (645.734 us; speedup 1.0000x reference)
//
#include <hip/hip_runtime.h>

#define NN_F 500
#define HID 64
#define NC 40
#define SCAN_T 256
#define SCAN_E 8
#define SCAN_B (SCAN_T * SCAN_E)
#define LDS_S 40   // LDS row stride in shorts (80 B): conflict-free MFMA fragment reads

typedef short s8v __attribute__((ext_vector_type(8)));
typedef short s4v __attribute__((ext_vector_type(4)));
typedef float f4v __attribute__((ext_vector_type(4)));

__device__ __forceinline__ unsigned short rne_bf16(float x) {
    unsigned u = __float_as_uint(x);
    return (unsigned short)((u + 0x7fffu + ((u >> 16) & 1u)) >> 16);
}
__device__ __forceinline__ float bf16_lo(unsigned v) {   // low 16 bits as bf16
    return __uint_as_float(v << 16);
}
__device__ __forceinline__ float bf16_hi(unsigned v) {   // high 16 bits as bf16
    return __uint_as_float(v & 0xffff0000u);
}

// ---- edge_index may arrive as int32 (harness-converted) or raw int64. ----
__device__ __forceinline__ int load_edge(const void* ei, long long idx, int is64) {
    if (is64) return (int)((const long long*)ei)[idx];
    return ((const int*)ei)[idx];
}

// Per-block inline int64 detection: sample high words of first 256 int64 slots.
// int64 indices < 2^31 -> high words all zero. int32 data there = actual indices,
// P(256 random indices all zero) ~ 0. Must be called by ALL threads of a 256-block.
__device__ __forceinline__ int detect_is64_block(const void* ei, int E) {
    const unsigned int* w = (const unsigned int*)ei;
    unsigned int acc = 0;
    int i = threadIdx.x;
    if (i < 256 && i < E) acc = w[2 * i + 1];
    int any = __any(acc != 0u);
    __shared__ int red[4];
    if ((threadIdx.x & 63) == 0) red[threadIdx.x >> 6] = any;
    __syncthreads();
    return (red[0] | red[1] | red[2] | red[3]) == 0;
}

// ---- deg histogram (+ inline detection) with W1-prep folded into grid tail ----
__global__ __launch_bounds__(256) void deg_wprep(const void* ei, int* __restrict__ deg,
                                                 const float* __restrict__ W1,
                                                 unsigned short* __restrict__ Wt1,
                                                 int E, int degBlocks) {
    if ((int)blockIdx.x >= degBlocks) {
        // Wt1[64][512] bf16 from W1[500][64] fp32 (transposed, zero-padded)
        int id = ((int)blockIdx.x - degBlocks) * 256 + threadIdx.x;
        if (id < 64 * 512) {
            int nn = id >> 9, k = id & 511;
            Wt1[id] = rne_bf16(k < NN_F ? W1[k * HID + nn] : 0.f);
        }
        return;
    }
    int is64 = detect_is64_block(ei, E);
    long long e = (long long)blockIdx.x * 256 + threadIdx.x;
    if (e < E) {
        int d = load_edge(ei, (long long)E + e, is64);
        atomicAdd(&deg[d], 1);
    }
}

// ---- scan phase 1: per-block partial exclusive scan of deg; dinv fused ----
__global__ __launch_bounds__(SCAN_T) void scan1(const int* __restrict__ deg,
                                                int* __restrict__ off,
                                                int* __restrict__ bsums,
                                                float* __restrict__ dinv, int n) {
    __shared__ int lds[SCAN_T];
    int base = blockIdx.x * SCAN_B + threadIdx.x * SCAN_E;
    int v[SCAN_E];
    int local = 0;
#pragma unroll
    for (int k = 0; k < SCAN_E; ++k) {
        int i = base + k;
        v[k] = (i < n) ? deg[i] : 0;
        if (i < n) dinv[i] = rsqrtf((float)v[k] + 1.0f);
        local += v[k];
    }
    lds[threadIdx.x] = local;
    __syncthreads();
    for (int o = 1; o < SCAN_T; o <<= 1) {
        int t = (threadIdx.x >= o) ? lds[threadIdx.x - o] : 0;
        __syncthreads();
        lds[threadIdx.x] += t;
        __syncthreads();
    }
    int prefix = lds[threadIdx.x] - local;
    if (threadIdx.x == SCAN_T - 1) bsums[blockIdx.x] = lds[threadIdx.x];
    int run = prefix;
#pragma unroll
    for (int k = 0; k < SCAN_E; ++k) {
        if (base + k < n) { off[base + k] = run; run += v[k]; }
    }
}

// ---- merged scan phases 2+3 (nb <= 64): every wave redundantly reduces the
//      block-sum prefix (<=64 ints, L2-hot), then applies to its elements ----
__global__ __launch_bounds__(SCAN_T) void scan_fin(int* __restrict__ off,
                                                   int* __restrict__ cur,
                                                   const int* __restrict__ bsums,
                                                   int n, int nb) {
    const int lane = threadIdx.x & 63;
    int v = (lane < nb && lane < (int)blockIdx.x) ? bsums[lane] : 0;
#pragma unroll
    for (int o = 1; o < 64; o <<= 1) v += __shfl_xor(v, o);
    const int add = v;
    if ((int)blockIdx.x == nb - 1 && threadIdx.x == 0) off[n] = add + bsums[nb - 1];
    int base = blockIdx.x * SCAN_B + threadIdx.x * SCAN_E;
#pragma unroll
    for (int k = 0; k < SCAN_E; ++k) {
        int i = base + k;
        if (i < n) { int t = off[i] + add; off[i] = t; cur[i] = t; }
    }
}

// fallback path (nb > 64) — kept for robustness
__global__ void scan2(int* bsums, int* off, int nb, int n) {
    if (threadIdx.x == 0 && blockIdx.x == 0) {
        int run = 0;
        for (int i = 0; i < nb; ++i) { int t = bsums[i]; bsums[i] = run; run += t; }
        off[n] = run;
    }
}
__global__ __launch_bounds__(SCAN_T) void scan3(int* __restrict__ off,
                                                int* __restrict__ cur,
                                                const int* __restrict__ bsums, int n) {
    int base = blockIdx.x * SCAN_B + threadIdx.x * SCAN_E;
    int add = bsums[blockIdx.x];
#pragma unroll
    for (int k = 0; k < SCAN_E; ++k) {
        int i = base + k;
        if (i < n) { int v = off[i] + add; off[i] = v; cur[i] = v; }
    }
}

// Scatter edges into CSR buckets by dst. Packed {src, weight_bits} single 8B store.
__global__ __launch_bounds__(256) void build_kernel(const void* ei,
                                                    const float* __restrict__ dinv,
                                                    int* __restrict__ cur,
                                                    int2* __restrict__ csr, int E) {
    int is64 = detect_is64_block(ei, E);
    long long e = (long long)blockIdx.x * 256 + threadIdx.x;
    if (e >= E) return;
    int s = load_edge(ei, e, is64);
    int d = load_edge(ei, (long long)E + e, is64);
    int pos = atomicAdd(&cur[d], 1);
    csr[pos] = make_int2(s, (int)__float_as_uint(dinv[s] * dinv[d]));
}

// ---- MFMA GEMM layer 1: h1[n x 64](bf16) = x[n x 500](fp32) @ Wt1^T ----
// 64-row blocks (2x the resident blocks/CU of the old 128-row version -> better
// latency hiding for this memory-bound 200MB stream). 4 waves x 16 rows.
__global__ __launch_bounds__(256) void gemm_mfma(const float* __restrict__ A,
                                                 const unsigned short* __restrict__ Wh,
                                                 unsigned short* __restrict__ out,
                                                 int n, int K) {
    __shared__ unsigned short Xh[64 * LDS_S];
    __shared__ unsigned short Bh[64 * LDS_S];
    const int t = threadIdx.x;
    const int row0 = blockIdx.x * 64;
    const int wid = t >> 6, lane = t & 63, q = lane >> 4, nn = lane & 15;

    f4v acc[4];
#pragma unroll
    for (int ct = 0; ct < 4; ++ct) acc[ct] = (f4v){0.f, 0.f, 0.f, 0.f};

    for (int k0 = 0; k0 < 512; k0 += 32) {
        {
            int bn = t >> 2, kq = t & 3;
            *(s8v*)&Bh[bn * LDS_S + kq * 8] = *(const s8v*)&Wh[bn * 512 + k0 + kq * 8];
        }
        {
            int kq = t & 7, rbase = t >> 3;
#pragma unroll
            for (int rr = 0; rr < 2; ++rr) {
                int row = rr * 32 + rbase;
                int grow = row0 + row;
                int k = k0 + kq * 4;
                float v0 = 0.f, v1 = 0.f, v2 = 0.f, v3 = 0.f;
                if (grow < n) {
                    if (k + 4 <= K) {
                        float4 v = *(const float4*)&A[(long long)grow * K + k];
                        v0 = v.x; v1 = v.y; v2 = v.z; v3 = v.w;
                    } else {
                        if (k + 0 < K) v0 = A[(long long)grow * K + k + 0];
                        if (k + 1 < K) v1 = A[(long long)grow * K + k + 1];
                        if (k + 2 < K) v2 = A[(long long)grow * K + k + 2];
                        if (k + 3 < K) v3 = A[(long long)grow * K + k + 3];
                    }
                }
                s4v h4;
                h4[0] = (short)rne_bf16(v0);
                h4[1] = (short)rne_bf16(v1);
                h4[2] = (short)rne_bf16(v2);
                h4[3] = (short)rne_bf16(v3);
                *(s4v*)&Xh[row * LDS_S + kq * 4] = h4;
            }
        }
        __syncthreads();

        const s8v ah = *(const s8v*)&Xh[(wid * 16 + nn) * LDS_S + q * 8];
#pragma unroll
        for (int ct = 0; ct < 4; ++ct) {
            const s8v bh = *(const s8v*)&Bh[(ct * 16 + nn) * LDS_S + q * 8];
            acc[ct] = __builtin_amdgcn_mfma_f32_16x16x32_bf16(ah, bh, acc[ct], 0, 0, 0);
        }
        __syncthreads();
    }

    // epilogue: C/D layout col=lane&15, row=(lane>>4)*4+r; store bf16
#pragma unroll
    for (int ct = 0; ct < 4; ++ct)
#pragma unroll
        for (int r = 0; r < 4; ++r) {
            int row = row0 + wid * 16 + q * 4 + r;
            if (row < n) out[(long long)row * 64 + ct * 16 + nn] = rne_bf16(acc[ct][r]);
        }
}

// Layer-1 gather FUSED with the layer-2 transform: per node,
//   v = relu(sum_edges norm*h1[src] + dinv^2*h1[node] + b1)   (64-vec, in wave regs)
//   h2[node][c] = sum_f v[f] * W2[f][c]                        (W2 fp32 in LDS)
// Eliminates the agg1 round-trip (51 MB) and the second MFMA GEMM entirely.
// h2 cols 40..63 are written as 0.
__global__ __launch_bounds__(256) void gather_l1w2(const int2* __restrict__ csr,
                                                   const int* __restrict__ off,
                                                   const unsigned short* __restrict__ h,
                                                   const float* __restrict__ dinv,
                                                   const float* __restrict__ b,
                                                   const float* __restrict__ W2,
                                                   unsigned short* __restrict__ h2, int n) {
    __shared__ float W2s[HID * NC];   // 64 x 40 fp32 = 10.2 KB
    for (int i = threadIdx.x; i < HID * NC; i += 256) W2s[i] = W2[i];
    __syncthreads();

    const int lane = threadIdx.x & 63;
    const int g = lane >> 4, fp = lane & 15;
    const int node = __builtin_amdgcn_readfirstlane(blockIdx.x * 4 + (threadIdx.x >> 6));
    if (node >= n) return;
    const int start = off[node], end = off[node + 1];
    f4v acc = (f4v){0.f, 0.f, 0.f, 0.f};
    int j = start;
    for (; j + 8 <= end; j += 8) {
        int2 ea = csr[j + g];
        int2 eb = csr[j + 4 + g];
        uint2 ha = *(const uint2*)(h + (long long)ea.x * 64 + fp * 4);
        uint2 hb = *(const uint2*)(h + (long long)eb.x * 64 + fp * 4);
        float wa = __uint_as_float((unsigned)ea.y);
        float wb = __uint_as_float((unsigned)eb.y);
        acc[0] = fmaf(wa, bf16_lo(ha.x), acc[0]);
        acc[1] = fmaf(wa, bf16_hi(ha.x), acc[1]);
        acc[2] = fmaf(wa, bf16_lo(ha.y), acc[2]);
        acc[3] = fmaf(wa, bf16_hi(ha.y), acc[3]);
        acc[0] = fmaf(wb, bf16_lo(hb.x), acc[0]);
        acc[1] = fmaf(wb, bf16_hi(hb.x), acc[1]);
        acc[2] = fmaf(wb, bf16_lo(hb.y), acc[2]);
        acc[3] = fmaf(wb, bf16_hi(hb.y), acc[3]);
    }
    for (; j < end; j += 4) {
        int jj = j + g;
        int2 e = csr[jj < end ? jj : end - 1];
        float w = (jj < end) ? __uint_as_float((unsigned)e.y) : 0.f;
        uint2 hv = *(const uint2*)(h + (long long)e.x * 64 + fp * 4);
        acc[0] = fmaf(w, bf16_lo(hv.x), acc[0]);
        acc[1] = fmaf(w, bf16_hi(hv.x), acc[1]);
        acc[2] = fmaf(w, bf16_lo(hv.y), acc[2]);
        acc[3] = fmaf(w, bf16_hi(hv.y), acc[3]);
    }
#pragma unroll
    for (int k = 0; k < 4; ++k) {
        acc[k] += __shfl_xor(acc[k], 16);
        acc[k] += __shfl_xor(acc[k], 32);
    }
    // self-loop + bias + relu  -> v (features 4fp..4fp+3, replicated over g)
    float dv = dinv[node];
    uint2 hn = *(const uint2*)(h + (long long)node * 64 + fp * 4);
    acc[0] = fmaf(dv * dv, bf16_lo(hn.x), acc[0]);
    acc[1] = fmaf(dv * dv, bf16_hi(hn.x), acc[1]);
    acc[2] = fmaf(dv * dv, bf16_lo(hn.y), acc[2]);
    acc[3] = fmaf(dv * dv, bf16_hi(hn.y), acc[3]);
    float4 b4 = ((const float4*)b)[fp];
    float v0 = acc[0] + b4.x; v0 = v0 > 0.f ? v0 : 0.f;
    float v1 = acc[1] + b4.y; v1 = v1 > 0.f ? v1 : 0.f;
    float v2 = acc[2] + b4.z; v2 = v2 > 0.f ? v2 : 0.f;
    float v3 = acc[3] + b4.w; v3 = v3 > 0.f ? v3 : 0.f;

    // wave-local dense transform: lane l computes h2 col l (l<40; others 0)
    float hcol = 0.f;
#pragma unroll
    for (int fp0 = 0; fp0 < 16; ++fp0) {
        float a0 = __shfl(v0, fp0);
        float a1 = __shfl(v1, fp0);
        float a2 = __shfl(v2, fp0);
        float a3 = __shfl(v3, fp0);
        if (lane < NC) {
            hcol = fmaf(a0, W2s[(4 * fp0 + 0) * NC + lane], hcol);
            hcol = fmaf(a1, W2s[(4 * fp0 + 1) * NC + lane], hcol);
            hcol = fmaf(a2, W2s[(4 * fp0 + 2) * NC + lane], hcol);
            hcol = fmaf(a3, W2s[(4 * fp0 + 3) * NC + lane], hcol);
        }
    }
    h2[(long long)node * 64 + lane] = rne_bf16(hcol);   // lanes >= NC store 0
}

// Layer-2 gather fused with bias, relu, log_softmax. h2 cols 0..39 valid; loads
// trimmed to fp<10 (80B/edge instead of 128B).
__global__ __launch_bounds__(256) void gather_l2(const int2* __restrict__ csr,
                                                 const int* __restrict__ off,
                                                 const unsigned short* __restrict__ h,
                                                 const float* __restrict__ dinv,
                                                 const float* __restrict__ b,
                                                 float* __restrict__ out, int n) {
    const int lane = threadIdx.x & 63;
    const int g = lane >> 4, fp = lane & 15;
    const int node = __builtin_amdgcn_readfirstlane(blockIdx.x * 4 + (threadIdx.x >> 6));
    if (node >= n) return;
    const int start = off[node], end = off[node + 1];
    f4v acc = (f4v){0.f, 0.f, 0.f, 0.f};
    int j = start;
    for (; j + 8 <= end; j += 8) {
        int2 ea = csr[j + g];
        int2 eb = csr[j + 4 + g];
        if (fp < 10) {
            uint2 ha = *(const uint2*)(h + (long long)ea.x * 64 + fp * 4);
            uint2 hb = *(const uint2*)(h + (long long)eb.x * 64 + fp * 4);
            float wa = __uint_as_float((unsigned)ea.y);
            float wb = __uint_as_float((unsigned)eb.y);
            acc[0] = fmaf(wa, bf16_lo(ha.x), acc[0]);
            acc[1] = fmaf(wa, bf16_hi(ha.x), acc[1]);
            acc[2] = fmaf(wa, bf16_lo(ha.y), acc[2]);
            acc[3] = fmaf(wa, bf16_hi(ha.y), acc[3]);
            acc[0] = fmaf(wb, bf16_lo(hb.x), acc[0]);
            acc[1] = fmaf(wb, bf16_hi(hb.x), acc[1]);
            acc[2] = fmaf(wb, bf16_lo(hb.y), acc[2]);
            acc[3] = fmaf(wb, bf16_hi(hb.y), acc[3]);
        }
    }
    for (; j < end; j += 4) {
        int jj = j + g;
        int2 e = csr[jj < end ? jj : end - 1];
        if (fp < 10) {
            float w = (jj < end) ? __uint_as_float((unsigned)e.y) : 0.f;
            uint2 hv = *(const uint2*)(h + (long long)e.x * 64 + fp * 4);
            acc[0] = fmaf(w, bf16_lo(hv.x), acc[0]);
            acc[1] = fmaf(w, bf16_hi(hv.x), acc[1]);
            acc[2] = fmaf(w, bf16_lo(hv.y), acc[2]);
            acc[3] = fmaf(w, bf16_hi(hv.y), acc[3]);
        }
    }
#pragma unroll
    for (int k = 0; k < 4; ++k) {
        acc[k] += __shfl_xor(acc[k], 16);
        acc[k] += __shfl_xor(acc[k], 32);
    }
    float dv = dinv[node];
    if (fp < 10) {
        uint2 hn = *(const uint2*)(h + (long long)node * 64 + fp * 4);
        acc[0] = fmaf(dv * dv, bf16_lo(hn.x), acc[0]);
        acc[1] = fmaf(dv * dv, bf16_hi(hn.x), acc[1]);
        acc[2] = fmaf(dv * dv, bf16_lo(hn.y), acc[2]);
        acc[3] = fmaf(dv * dv, bf16_hi(hn.y), acc[3]);
    }
    // bias + relu for features fp*4..fp*4+3 (valid iff fp < 10 since NC=40)
    float t0, t1, t2, t3;
    if (fp < 10) {
        float4 b4 = ((const float4*)b)[fp];
        t0 = acc[0] + b4.x; t0 = t0 > 0.f ? t0 : 0.f;
        t1 = acc[1] + b4.y; t1 = t1 > 0.f ? t1 : 0.f;
        t2 = acc[2] + b4.z; t2 = t2 > 0.f ? t2 : 0.f;
        t3 = acc[3] + b4.w; t3 = t3 > 0.f ? t3 : 0.f;
    } else {
        t0 = t1 = t2 = t3 = -1e30f;
    }
    float m = fmaxf(fmaxf(t0, t1), fmaxf(t2, t3));
#pragma unroll
    for (int o = 1; o < 16; o <<= 1) m = fmaxf(m, __shfl_xor(m, o));
    float ssum = 0.f;
    if (fp < 10) ssum = expf(t0 - m) + expf(t1 - m) + expf(t2 - m) + expf(t3 - m);
#pragma unroll
    for (int o = 1; o < 16; o <<= 1) ssum += __shfl_xor(ssum, o);
    if (g == 0 && fp < 10) {
        float ls = m + logf(ssum);
        float4 v = make_float4(t0 - ls, t1 - ls, t2 - ls, t3 - ls);
        ((float4*)(out + (long long)node * NC))[fp] = v;
    }
}

static inline char* align256(char* p) {
    return (char*)(((uintptr_t)p + 255) & ~(uintptr_t)255);
}

extern "C" void kernel_launch(void* const* d_in, const int* in_sizes, int n_in,
                              void* d_out, int out_size, void* d_ws, size_t ws_size,
                              hipStream_t stream) {
    const float* x  = (const float*)d_in[0];
    const void*  ei = d_in[1];
    const float* W1 = (const float*)d_in[2];
    const float* b1 = (const float*)d_in[3];
    const float* W2 = (const float*)d_in[4];
    const float* b2 = (const float*)d_in[5];
    float* out = (float*)d_out;
    const int n = in_sizes[0] / NN_F;   // 100000
    const int E = in_sizes[1] / 2;      // 1600000
    const int nScanBlocks = (n + SCAN_B - 1) / SCAN_B;
    const int degBlocks = (E + 255) / 256;

    char* p = (char*)d_ws;
    int* deg  = (int*)p;                 p = align256(p + (size_t)n * sizeof(int));
    int* off  = (int*)p;                 p = align256(p + (size_t)(n + 1) * sizeof(int));
    int* cur  = (int*)p;                 p = align256(p + (size_t)n * sizeof(int));
    int* bsums = (int*)p;                p = align256(p + 256 * sizeof(int));
    float* dinv = (float*)p;             p = align256(p + (size_t)n * sizeof(float));
    int2* csr = (int2*)p;                p = align256(p + (size_t)E * sizeof(int2));
    unsigned short* Wt1 = (unsigned short*)p; p = align256(p + (size_t)64 * 512 * sizeof(short));
    unsigned short* h1 = (unsigned short*)p; p = align256(p + (size_t)n * 64 * sizeof(unsigned short));
    unsigned short* h2 = (unsigned short*)p; p = align256(p + (size_t)n * 64 * sizeof(unsigned short));

    (void)hipMemsetAsync(deg, 0, (size_t)n * sizeof(int), stream);
    deg_wprep<<<degBlocks + 128, 256, 0, stream>>>(ei, deg, W1, Wt1, E, degBlocks);

    scan1<<<nScanBlocks, SCAN_T, 0, stream>>>(deg, off, bsums, dinv, n);
    if (nScanBlocks <= 64) {
        scan_fin<<<nScanBlocks, SCAN_T, 0, stream>>>(off, cur, bsums, n, nScanBlocks);
    } else {
        scan2<<<1, 64, 0, stream>>>(bsums, off, nScanBlocks, n);
        scan3<<<nScanBlocks, SCAN_T, 0, stream>>>(off, cur, bsums, n);
    }
    build_kernel<<<degBlocks, 256, 0, stream>>>(ei, dinv, cur, csr, E);

    gemm_mfma<<<(n + 63) / 64, 256, 0, stream>>>(x, Wt1, h1, n, NN_F);
    gather_l1w2<<<(n + 3) / 4, 256, 0, stream>>>(csr, off, h1, dinv, b1, W2, h2, n);
    gather_l2<<<(n + 3) / 4, 256, 0, stream>>>(csr, off, h2, dinv, b2, out, n);
}

// Round 3
// 575.128 us; speedup vs baseline: 1.1228x; 1.1228x over previous
//
#include <hip/hip_runtime.h>

#define NN_F 500
#define HID 64
#define NC 40
#define SCAN_T 256
#define SCAN_E 8
#define SCAN_B (SCAN_T * SCAN_E)
#define LDS_S 40   // LDS row stride in shorts (80 B): conflict-free MFMA fragment reads

typedef short s8v __attribute__((ext_vector_type(8)));
typedef short s4v __attribute__((ext_vector_type(4)));
typedef float f4v __attribute__((ext_vector_type(4)));

__device__ __forceinline__ unsigned short rne_bf16(float x) {
    unsigned u = __float_as_uint(x);
    return (unsigned short)((u + 0x7fffu + ((u >> 16) & 1u)) >> 16);
}
__device__ __forceinline__ float bf16_lo(unsigned v) {   // low 16 bits as bf16
    return __uint_as_float(v << 16);
}
__device__ __forceinline__ float bf16_hi(unsigned v) {   // high 16 bits as bf16
    return __uint_as_float(v & 0xffff0000u);
}

// ---- edge_index may arrive as int32 (harness-converted) or raw int64. ----
__device__ __forceinline__ int load_edge(const void* ei, long long idx, int is64) {
    if (is64) return (int)((const long long*)ei)[idx];
    return ((const int*)ei)[idx];
}

__global__ __launch_bounds__(256) void detect_kernel(const unsigned int* w, int* flag) {
    __shared__ unsigned int red[256];
    unsigned int acc = 0;
    for (int i = threadIdx.x; i < 2048; i += 256) acc |= w[2 * i + 1];
    red[threadIdx.x] = acc;
    __syncthreads();
    for (int s = 128; s > 0; s >>= 1) {
        if (threadIdx.x < s) red[threadIdx.x] |= red[threadIdx.x + s];
        __syncthreads();
    }
    if (threadIdx.x == 0) flag[0] = (red[0] == 0u) ? 1 : 0;
}

__global__ __launch_bounds__(256) void deg_kernel(const void* ei, const int* flag,
                                                  int* deg, int E) {
    int is64 = flag[0];
    long long e = (long long)blockIdx.x * 256 + threadIdx.x;
    if (e < E) {
        int d = load_edge(ei, (long long)E + e, is64);
        atomicAdd(&deg[d], 1);
    }
}

// ---- 3-phase exclusive scan of deg -> off; dinv fused into phase 1 ----
__global__ __launch_bounds__(SCAN_T) void scan1(const int* __restrict__ deg,
                                                int* __restrict__ off,
                                                int* __restrict__ bsums,
                                                float* __restrict__ dinv, int n) {
    __shared__ int lds[SCAN_T];
    int base = blockIdx.x * SCAN_B + threadIdx.x * SCAN_E;
    int v[SCAN_E];
    int local = 0;
#pragma unroll
    for (int k = 0; k < SCAN_E; ++k) {
        int i = base + k;
        v[k] = (i < n) ? deg[i] : 0;
        if (i < n) dinv[i] = rsqrtf((float)v[k] + 1.0f);
        local += v[k];
    }
    lds[threadIdx.x] = local;
    __syncthreads();
    for (int o = 1; o < SCAN_T; o <<= 1) {
        int t = (threadIdx.x >= o) ? lds[threadIdx.x - o] : 0;
        __syncthreads();
        lds[threadIdx.x] += t;
        __syncthreads();
    }
    int prefix = lds[threadIdx.x] - local;
    if (threadIdx.x == SCAN_T - 1) bsums[blockIdx.x] = lds[threadIdx.x];
    int run = prefix;
#pragma unroll
    for (int k = 0; k < SCAN_E; ++k) {
        if (base + k < n) { off[base + k] = run; run += v[k]; }
    }
}

// Single-wave parallel scan over block sums (nb <= 64 in practice; serial fallback kept).
__global__ void scan2(int* bsums, int* off, int nb, int n) {
    int lane = threadIdx.x;
    if (nb <= 64) {
        int v = (lane < nb) ? bsums[lane] : 0;
        int incl = v;
#pragma unroll
        for (int o = 1; o < 64; o <<= 1) {
            int t = __shfl_up(incl, o);
            if (lane >= o) incl += t;
        }
        if (lane < nb) bsums[lane] = incl - v;
        if (lane == 63) off[n] = incl;
    } else if (lane == 0) {
        int run = 0;
        for (int i = 0; i < nb; ++i) { int t = bsums[i]; bsums[i] = run; run += t; }
        off[n] = run;
    }
}

__global__ __launch_bounds__(SCAN_T) void scan3(int* __restrict__ off,
                                                int* __restrict__ cur,
                                                const int* __restrict__ bsums, int n) {
    int base = blockIdx.x * SCAN_B + threadIdx.x * SCAN_E;
    int add = bsums[blockIdx.x];
#pragma unroll
    for (int k = 0; k < SCAN_E; ++k) {
        int i = base + k;
        if (i < n) { int v = off[i] + add; off[i] = v; cur[i] = v; }
    }
}

// Scatter edges into CSR buckets by dst. Packed {src, weight_bits} single 8B store.
__global__ __launch_bounds__(256) void build_kernel(const void* ei, const int* flag,
                                                    const float* __restrict__ dinv,
                                                    int* __restrict__ cur,
                                                    int2* __restrict__ csr, int E) {
    int is64 = flag[0];
    long long e = (long long)blockIdx.x * 256 + threadIdx.x;
    if (e >= E) return;
    int s = load_edge(ei, e, is64);
    int d = load_edge(ei, (long long)E + e, is64);
    int pos = atomicAdd(&cur[d], 1);
    csr[pos] = make_int2(s, (int)__float_as_uint(dinv[s] * dinv[d]));
}

// ---- W prep (both layers in one launch): fp32 [K][Nc] -> transposed bf16 [N][KP] ----
__global__ __launch_bounds__(256) void wprep2(const float* __restrict__ W1,
                                              const float* __restrict__ W2,
                                              unsigned short* __restrict__ Wt1,
                                              unsigned short* __restrict__ Wt2) {
    int id = blockIdx.x * 256 + threadIdx.x;
    if (id < 64 * 512) {
        int nn = id >> 9, k = id & 511;          // Wt1[64][512] from W1[500][64]
        float v = (k < NN_F) ? W1[k * HID + nn] : 0.f;
        Wt1[id] = rne_bf16(v);
    } else {
        int id2 = id - 64 * 512;
        if (id2 >= 64 * 64) return;
        int nn = id2 >> 6, k = id2 & 63;         // Wt2[64][64] from W2[64][40]
        float v = (nn < NC) ? W2[k * NC + nn] : 0.f;
        Wt2[id2] = rne_bf16(v);
    }
}

// ---- MFMA GEMM: out[n x 64](bf16) = A[n x K](fp32) @ Wt^T, pure bf16 ----
// Block tile: 128 rows x 64 cols, K-tile 32. 4 waves, each 32 rows x 64 cols.
template<int KPAD>
__global__ __launch_bounds__(256) void gemm_mfma(const float* __restrict__ A,
                                                 const unsigned short* __restrict__ Wh,
                                                 unsigned short* __restrict__ out,
                                                 int n, int K) {
    __shared__ unsigned short Xh[128 * LDS_S];
    __shared__ unsigned short Bh[64 * LDS_S];
    const int t = threadIdx.x;
    const int row0 = blockIdx.x * 128;
    const int wid = t >> 6, lane = t & 63, q = lane >> 4, nn = lane & 15;

    f4v acc[2][4];
#pragma unroll
    for (int mt = 0; mt < 2; ++mt)
#pragma unroll
        for (int ct = 0; ct < 4; ++ct) acc[mt][ct] = (f4v){0.f, 0.f, 0.f, 0.f};

    for (int k0 = 0; k0 < KPAD; k0 += 32) {
        {
            int bn = t >> 2, kq = t & 3;
            *(s8v*)&Bh[bn * LDS_S + kq * 8] = *(const s8v*)&Wh[bn * KPAD + k0 + kq * 8];
        }
        {
            int kq = t & 7, rbase = t >> 3;
#pragma unroll
            for (int rr = 0; rr < 4; ++rr) {
                int row = rr * 32 + rbase;
                int grow = row0 + row;
                int k = k0 + kq * 4;
                float v0 = 0.f, v1 = 0.f, v2 = 0.f, v3 = 0.f;
                if (grow < n) {
                    if (k + 4 <= K) {
                        float4 v = *(const float4*)&A[(long long)grow * K + k];
                        v0 = v.x; v1 = v.y; v2 = v.z; v3 = v.w;
                    } else {
                        if (k + 0 < K) v0 = A[(long long)grow * K + k + 0];
                        if (k + 1 < K) v1 = A[(long long)grow * K + k + 1];
                        if (k + 2 < K) v2 = A[(long long)grow * K + k + 2];
                        if (k + 3 < K) v3 = A[(long long)grow * K + k + 3];
                    }
                }
                s4v h4;
                h4[0] = (short)rne_bf16(v0);
                h4[1] = (short)rne_bf16(v1);
                h4[2] = (short)rne_bf16(v2);
                h4[3] = (short)rne_bf16(v3);
                *(s4v*)&Xh[row * LDS_S + kq * 4] = h4;
            }
        }
        __syncthreads();

        const s8v ah0 = *(const s8v*)&Xh[(wid * 32 + nn) * LDS_S + q * 8];
        const s8v ah1 = *(const s8v*)&Xh[(wid * 32 + 16 + nn) * LDS_S + q * 8];
#pragma unroll
        for (int ct = 0; ct < 4; ++ct) {
            const s8v bh = *(const s8v*)&Bh[(ct * 16 + nn) * LDS_S + q * 8];
            acc[0][ct] = __builtin_amdgcn_mfma_f32_16x16x32_bf16(ah0, bh, acc[0][ct], 0, 0, 0);
            acc[1][ct] = __builtin_amdgcn_mfma_f32_16x16x32_bf16(ah1, bh, acc[1][ct], 0, 0, 0);
        }
        __syncthreads();
    }

    // epilogue: C/D layout col=lane&15, row=(lane>>4)*4+r; store bf16
#pragma unroll
    for (int mt = 0; mt < 2; ++mt)
#pragma unroll
        for (int ct = 0; ct < 4; ++ct)
#pragma unroll
            for (int r = 0; r < 4; ++r) {
                int row = row0 + wid * 32 + mt * 16 + q * 4 + r;
                if (row < n) out[(long long)row * 64 + ct * 16 + nn] = rne_bf16(acc[mt][ct][r]);
            }
}

#define FMA8(W, H)                                          \
    acc[0] = fmaf(W, bf16_lo((H).x), acc[0]);               \
    acc[1] = fmaf(W, bf16_hi((H).x), acc[1]);               \
    acc[2] = fmaf(W, bf16_lo((H).y), acc[2]);               \
    acc[3] = fmaf(W, bf16_hi((H).y), acc[3]);               \
    acc[4] = fmaf(W, bf16_lo((H).z), acc[4]);               \
    acc[5] = fmaf(W, bf16_hi((H).z), acc[5]);               \
    acc[6] = fmaf(W, bf16_lo((H).w), acc[6]);               \
    acc[7] = fmaf(W, bf16_hi((H).w), acc[7])

// Layer-1 gather: wave per node. 8 edge slots (g=lane>>3) x 8-feature octets
// (fl=lane&7, 16B uint4 row loads). 16 edges in flight per main-loop iteration
// (2x the old 16-lane/8B scheme) -> latency-bound gather gets 2x MLP with half
// the load instructions per byte. Reduce across slots with shfl_xor(8/16/32).
__global__ __launch_bounds__(256) void gather_l1(const int2* __restrict__ csr,
                                                 const int* __restrict__ off,
                                                 const unsigned short* __restrict__ h,
                                                 const float* __restrict__ dinv,
                                                 const float* __restrict__ b,
                                                 float* __restrict__ agg, int n) {
    const int lane = threadIdx.x & 63;
    const int g = lane >> 3, fl = lane & 7;
    const int node = __builtin_amdgcn_readfirstlane(blockIdx.x * 4 + (threadIdx.x >> 6));
    if (node >= n) return;
    const int start = off[node], end = off[node + 1];
    float acc[8];
#pragma unroll
    for (int k = 0; k < 8; ++k) acc[k] = 0.f;
    int j = start;
    for (; j + 16 <= end; j += 16) {
        int2 ea = csr[j + g];
        int2 eb = csr[j + 8 + g];
        uint4 ha = *(const uint4*)(h + (long long)ea.x * 64 + fl * 8);
        uint4 hb = *(const uint4*)(h + (long long)eb.x * 64 + fl * 8);
        float wa = __uint_as_float((unsigned)ea.y);
        float wb = __uint_as_float((unsigned)eb.y);
        FMA8(wa, ha);
        FMA8(wb, hb);
    }
    for (; j < end; j += 8) {
        int jj = j + g;
        int2 e = csr[jj < end ? jj : end - 1];
        float w = (jj < end) ? __uint_as_float((unsigned)e.y) : 0.f;
        uint4 hv = *(const uint4*)(h + (long long)e.x * 64 + fl * 8);
        FMA8(w, hv);
    }
#pragma unroll
    for (int k = 0; k < 8; ++k) {
        acc[k] += __shfl_xor(acc[k], 8);
        acc[k] += __shfl_xor(acc[k], 16);
        acc[k] += __shfl_xor(acc[k], 32);
    }
    if (g == 0) {
        // self-loop + bias + relu; lane fl owns features fl*8..fl*8+7
        float dv = dinv[node];
        float w = dv * dv;
        uint4 hn = *(const uint4*)(h + (long long)node * 64 + fl * 8);
        FMA8(w, hn);
        float4 b4a = ((const float4*)b)[fl * 2];
        float4 b4b = ((const float4*)b)[fl * 2 + 1];
        float4 o0, o1;
        o0.x = acc[0] + b4a.x; o0.x = o0.x > 0.f ? o0.x : 0.f;
        o0.y = acc[1] + b4a.y; o0.y = o0.y > 0.f ? o0.y : 0.f;
        o0.z = acc[2] + b4a.z; o0.z = o0.z > 0.f ? o0.z : 0.f;
        o0.w = acc[3] + b4a.w; o0.w = o0.w > 0.f ? o0.w : 0.f;
        o1.x = acc[4] + b4b.x; o1.x = o1.x > 0.f ? o1.x : 0.f;
        o1.y = acc[5] + b4b.y; o1.y = o1.y > 0.f ? o1.y : 0.f;
        o1.z = acc[6] + b4b.z; o1.z = o1.z > 0.f ? o1.z : 0.f;
        o1.w = acc[7] + b4b.w; o1.w = o1.w > 0.f ? o1.w : 0.f;
        float4* dst = (float4*)(agg + (long long)node * 64 + fl * 8);
        dst[0] = o0;
        dst[1] = o1;
    }
}

// Layer-2 gather, same 8-slot structure; h2 cols 0..39 valid -> only lanes fl<5
// load (80B/row instead of 128B). Fused bias + relu + log_softmax.
__global__ __launch_bounds__(256) void gather_l2(const int2* __restrict__ csr,
                                                 const int* __restrict__ off,
                                                 const unsigned short* __restrict__ h,
                                                 const float* __restrict__ dinv,
                                                 const float* __restrict__ b,
                                                 float* __restrict__ out, int n) {
    const int lane = threadIdx.x & 63;
    const int g = lane >> 3, fl = lane & 7;
    const int node = __builtin_amdgcn_readfirstlane(blockIdx.x * 4 + (threadIdx.x >> 6));
    if (node >= n) return;
    const int start = off[node], end = off[node + 1];
    float acc[8];
#pragma unroll
    for (int k = 0; k < 8; ++k) acc[k] = 0.f;
    int j = start;
    for (; j + 16 <= end; j += 16) {
        int2 ea = csr[j + g];
        int2 eb = csr[j + 8 + g];
        if (fl < 5) {
            uint4 ha = *(const uint4*)(h + (long long)ea.x * 64 + fl * 8);
            uint4 hb = *(const uint4*)(h + (long long)eb.x * 64 + fl * 8);
            float wa = __uint_as_float((unsigned)ea.y);
            float wb = __uint_as_float((unsigned)eb.y);
            FMA8(wa, ha);
            FMA8(wb, hb);
        }
    }
    for (; j < end; j += 8) {
        int jj = j + g;
        int2 e = csr[jj < end ? jj : end - 1];
        if (fl < 5) {
            float w = (jj < end) ? __uint_as_float((unsigned)e.y) : 0.f;
            uint4 hv = *(const uint4*)(h + (long long)e.x * 64 + fl * 8);
            FMA8(w, hv);
        }
    }
#pragma unroll
    for (int k = 0; k < 8; ++k) {
        acc[k] += __shfl_xor(acc[k], 8);
        acc[k] += __shfl_xor(acc[k], 16);
        acc[k] += __shfl_xor(acc[k], 32);
    }
    // self-loop + bias + relu on owning lanes (g==0, fl<5), then 8-lane softmax
    float v[8];
    float vmax = -1e30f;
    if (fl < 5) {
        float dv = dinv[node];
        float w = dv * dv;
        uint4 hn = *(const uint4*)(h + (long long)node * 64 + fl * 8);
        FMA8(w, hn);
        float4 b4a = ((const float4*)b)[fl * 2];
        float4 b4b = ((const float4*)b)[fl * 2 + 1];
        v[0] = acc[0] + b4a.x; v[1] = acc[1] + b4a.y;
        v[2] = acc[2] + b4a.z; v[3] = acc[3] + b4a.w;
        v[4] = acc[4] + b4b.x; v[5] = acc[5] + b4b.y;
        v[6] = acc[6] + b4b.z; v[7] = acc[7] + b4b.w;
#pragma unroll
        for (int k = 0; k < 8; ++k) {
            v[k] = v[k] > 0.f ? v[k] : 0.f;
            vmax = fmaxf(vmax, v[k]);
        }
    }
#pragma unroll
    for (int o = 1; o < 8; o <<= 1) vmax = fmaxf(vmax, __shfl_xor(vmax, o));
    float ssum = 0.f;
    if (fl < 5) {
#pragma unroll
        for (int k = 0; k < 8; ++k) ssum += expf(v[k] - vmax);
    }
#pragma unroll
    for (int o = 1; o < 8; o <<= 1) ssum += __shfl_xor(ssum, o);
    if (g == 0 && fl < 5) {
        float ls = vmax + logf(ssum);
        float4 o0 = make_float4(v[0] - ls, v[1] - ls, v[2] - ls, v[3] - ls);
        float4 o1 = make_float4(v[4] - ls, v[5] - ls, v[6] - ls, v[7] - ls);
        float4* dst = (float4*)(out + (long long)node * NC + fl * 8);
        dst[0] = o0;
        dst[1] = o1;
    }
}

static inline char* align256(char* p) {
    return (char*)(((uintptr_t)p + 255) & ~(uintptr_t)255);
}

extern "C" void kernel_launch(void* const* d_in, const int* in_sizes, int n_in,
                              void* d_out, int out_size, void* d_ws, size_t ws_size,
                              hipStream_t stream) {
    const float* x  = (const float*)d_in[0];
    const void*  ei = d_in[1];
    const float* W1 = (const float*)d_in[2];
    const float* b1 = (const float*)d_in[3];
    const float* W2 = (const float*)d_in[4];
    const float* b2 = (const float*)d_in[5];
    float* out = (float*)d_out;
    const int n = in_sizes[0] / NN_F;   // 100000
    const int E = in_sizes[1] / 2;      // 1600000
    const int nScanBlocks = (n + SCAN_B - 1) / SCAN_B;

    char* p = (char*)d_ws;
    int* flag = (int*)p;                 p = align256(p + 16 * sizeof(int));
    int* deg  = (int*)p;                 p = align256(p + (size_t)n * sizeof(int));
    int* off  = (int*)p;                 p = align256(p + (size_t)(n + 1) * sizeof(int));
    int* cur  = (int*)p;                 p = align256(p + (size_t)n * sizeof(int));
    int* bsums = (int*)p;                p = align256(p + 256 * sizeof(int));
    float* dinv = (float*)p;             p = align256(p + (size_t)n * sizeof(float));
    int2* csr = (int2*)p;                p = align256(p + (size_t)E * sizeof(int2));
    unsigned short* Wt1 = (unsigned short*)p; p = align256(p + (size_t)64 * 512 * sizeof(short));
    unsigned short* Wt2 = (unsigned short*)p; p = align256(p + (size_t)64 * 64 * sizeof(short));
    unsigned short* h1 = (unsigned short*)p; p = align256(p + (size_t)n * 64 * sizeof(unsigned short));
    float* agg1 = (float*)p;             p = align256(p + (size_t)n * 64 * sizeof(float));
    unsigned short* h2 = h1;  // reuse: h1 dead after gather_l1

    (void)hipMemsetAsync(deg, 0, (size_t)n * sizeof(int), stream);
    detect_kernel<<<1, 256, 0, stream>>>((const unsigned int*)ei, flag);
    deg_kernel<<<(E + 255) / 256, 256, 0, stream>>>(ei, flag, deg, E);

    scan1<<<nScanBlocks, SCAN_T, 0, stream>>>(deg, off, bsums, dinv, n);
    scan2<<<1, 64, 0, stream>>>(bsums, off, nScanBlocks, n);
    scan3<<<nScanBlocks, SCAN_T, 0, stream>>>(off, cur, bsums, n);
    build_kernel<<<(E + 255) / 256, 256, 0, stream>>>(ei, flag, dinv, cur, csr, E);

    wprep2<<<(64 * 512 + 64 * 64 + 255) / 256, 256, 0, stream>>>(W1, W2, Wt1, Wt2);

    const int gBlocks = (n + 127) / 128;
    gemm_mfma<512><<<gBlocks, 256, 0, stream>>>(x, Wt1, h1, n, NN_F);
    gather_l1<<<(n + 3) / 4, 256, 0, stream>>>(csr, off, h1, dinv, b1, agg1, n);

    gemm_mfma<64><<<gBlocks, 256, 0, stream>>>(agg1, Wt2, h2, n, HID);
    gather_l2<<<(n + 3) / 4, 256, 0, stream>>>(csr, off, h2, dinv, b2, out, n);
}

// Round 5
// 549.685 us; speedup vs baseline: 1.1747x; 1.0463x over previous
//
#include <hip/hip_runtime.h>

#define NN_F 500
#define HID 64
#define NC 40
#define SCAN_T 256
#define SCAN_E 8
#define SCAN_B (SCAN_T * SCAN_E)
#define LDS_S 40   // LDS row stride in shorts (80 B): conflict-free MFMA fragment reads

typedef short s8v __attribute__((ext_vector_type(8)));
typedef short s4v __attribute__((ext_vector_type(4)));
typedef float f4v __attribute__((ext_vector_type(4)));

__device__ __forceinline__ unsigned short rne_bf16(float x) {
    unsigned u = __float_as_uint(x);
    return (unsigned short)((u + 0x7fffu + ((u >> 16) & 1u)) >> 16);
}
__device__ __forceinline__ float bf16_lo(unsigned v) {   // low 16 bits as bf16
    return __uint_as_float(v << 16);
}
__device__ __forceinline__ float bf16_hi(unsigned v) {   // high 16 bits as bf16
    return __uint_as_float(v & 0xffff0000u);
}

// ---- edge_index may arrive as int32 (harness-converted) or raw int64. ----
__device__ __forceinline__ int load_edge(const void* ei, long long idx, int is64) {
    if (is64) return (int)((const long long*)ei)[idx];
    return ((const int*)ei)[idx];
}

// Per-block inline int64 detection: sample high words of first 256 int64 slots.
// int64 indices < 2^31 -> high words all zero. int32 data there = actual indices;
// P(all sampled == 0) ~ 0. Must be called by ALL threads of a 256-block.
__device__ __forceinline__ int detect_is64_block(const void* ei, int E) {
    const unsigned int* w = (const unsigned int*)ei;
    unsigned int acc = 0;
    int i = threadIdx.x;
    if (i < 256 && i < E) acc = w[2 * i + 1];
    int any = __any(acc != 0u);
    __shared__ int red[4];
    if ((threadIdx.x & 63) == 0) red[threadIdx.x >> 6] = any;
    __syncthreads();
    return (red[0] | red[1] | red[2] | red[3]) == 0;
}

// ---- deg histogram (+inline detect) with BOTH weight preps folded into grid tail ----
__global__ __launch_bounds__(256) void deg_wprep(const void* ei, int* __restrict__ deg,
                                                 const float* __restrict__ W1,
                                                 const float* __restrict__ W2,
                                                 unsigned short* __restrict__ Wt1,
                                                 unsigned short* __restrict__ Wt2,
                                                 int E, int degBlocks) {
    if ((int)blockIdx.x >= degBlocks) {
        int id = ((int)blockIdx.x - degBlocks) * 256 + threadIdx.x;
        if (id < 64 * 512) {
            int nn = id >> 9, k = id & 511;          // Wt1[64][512] from W1[500][64]
            Wt1[id] = rne_bf16(k < NN_F ? W1[k * HID + nn] : 0.f);
        } else {
            int id2 = id - 64 * 512;
            if (id2 < 64 * 64) {
                int nn = id2 >> 6, k = id2 & 63;     // Wt2[64][64] from W2[64][40]
                Wt2[id2] = rne_bf16(nn < NC ? W2[k * NC + nn] : 0.f);
            }
        }
        return;
    }
    int is64 = detect_is64_block(ei, E);
    long long e = (long long)blockIdx.x * 256 + threadIdx.x;
    if (e < E) {
        int d = load_edge(ei, (long long)E + e, is64);
        atomicAdd(&deg[d], 1);
    }
}

// ---- scan phase 1: per-block partial exclusive scan of deg; dinv fused ----
__global__ __launch_bounds__(SCAN_T) void scan1(const int* __restrict__ deg,
                                                int* __restrict__ off,
                                                int* __restrict__ bsums,
                                                float* __restrict__ dinv, int n) {
    __shared__ int lds[SCAN_T];
    int base = blockIdx.x * SCAN_B + threadIdx.x * SCAN_E;
    int v[SCAN_E];
    int local = 0;
#pragma unroll
    for (int k = 0; k < SCAN_E; ++k) {
        int i = base + k;
        v[k] = (i < n) ? deg[i] : 0;
        if (i < n) dinv[i] = rsqrtf((float)v[k] + 1.0f);
        local += v[k];
    }
    lds[threadIdx.x] = local;
    __syncthreads();
    for (int o = 1; o < SCAN_T; o <<= 1) {
        int t = (threadIdx.x >= o) ? lds[threadIdx.x - o] : 0;
        __syncthreads();
        lds[threadIdx.x] += t;
        __syncthreads();
    }
    int prefix = lds[threadIdx.x] - local;
    if (threadIdx.x == SCAN_T - 1) bsums[blockIdx.x] = lds[threadIdx.x];
    int run = prefix;
#pragma unroll
    for (int k = 0; k < SCAN_E; ++k) {
        if (base + k < n) { off[base + k] = run; run += v[k]; }
    }
}

// ---- merged scan phases 2+3 (nb <= 64): every wave redundantly reduces the
//      block-sum prefix (<=64 ints, L2-hot), then applies to its elements ----
__global__ __launch_bounds__(SCAN_T) void scan_fin(int* __restrict__ off,
                                                   int* __restrict__ cur,
                                                   const int* __restrict__ bsums,
                                                   int n, int nb) {
    const int lane = threadIdx.x & 63;
    int v = (lane < nb && lane < (int)blockIdx.x) ? bsums[lane] : 0;
#pragma unroll
    for (int o = 1; o < 64; o <<= 1) v += __shfl_xor(v, o);
    const int add = v;
    if ((int)blockIdx.x == nb - 1 && threadIdx.x == 0) off[n] = add + bsums[nb - 1];
    int base = blockIdx.x * SCAN_B + threadIdx.x * SCAN_E;
#pragma unroll
    for (int k = 0; k < SCAN_E; ++k) {
        int i = base + k;
        if (i < n) { int t = off[i] + add; off[i] = t; cur[i] = t; }
    }
}

// fallback path (nb > 64) — kept for robustness
__global__ void scan2(int* bsums, int* off, int nb, int n) {
    if (threadIdx.x == 0 && blockIdx.x == 0) {
        int run = 0;
        for (int i = 0; i < nb; ++i) { int t = bsums[i]; bsums[i] = run; run += t; }
        off[n] = run;
    }
}
__global__ __launch_bounds__(SCAN_T) void scan3(int* __restrict__ off,
                                                int* __restrict__ cur,
                                                const int* __restrict__ bsums, int n) {
    int base = blockIdx.x * SCAN_B + threadIdx.x * SCAN_E;
    int add = bsums[blockIdx.x];
#pragma unroll
    for (int k = 0; k < SCAN_E; ++k) {
        int i = base + k;
        if (i < n) { int v = off[i] + add; off[i] = v; cur[i] = v; }
    }
}

// ---- shared MFMA GEMM tile body: out[128 x OUTW](bf16) = A[128 x K] @ Wh^T ----
// A fp32 (with rne conversion in staging) or bf16 (direct 16B copies).
// OUTW is both the out row stride and the valid column count.
template<int KPAD, bool ABF16, int OUTW>
__device__ __forceinline__ void gemm_tile(const void* Av,
                                          const unsigned short* __restrict__ Wh,
                                          unsigned short* __restrict__ out,
                                          int n, int K, int bIdx,
                                          unsigned short* Xh, unsigned short* Bh) {
    const int t = threadIdx.x;
    const int row0 = bIdx * 128;
    const int wid = t >> 6, lane = t & 63, q = lane >> 4, nn = lane & 15;

    f4v acc[2][4];
#pragma unroll
    for (int mt = 0; mt < 2; ++mt)
#pragma unroll
        for (int ct = 0; ct < 4; ++ct) acc[mt][ct] = (f4v){0.f, 0.f, 0.f, 0.f};

    for (int k0 = 0; k0 < KPAD; k0 += 32) {
        {
            int bn = t >> 2, kq = t & 3;
            *(s8v*)&Bh[bn * LDS_S + kq * 8] = *(const s8v*)&Wh[bn * KPAD + k0 + kq * 8];
        }
        if (ABF16) {
            const unsigned short* A = (const unsigned short*)Av;
            int kq = t & 3, rbase = t >> 2;
#pragma unroll
            for (int rr = 0; rr < 2; ++rr) {
                int row = rr * 64 + rbase;
                int grow = row0 + row;
                s8v h8 = (s8v){0, 0, 0, 0, 0, 0, 0, 0};
                if (grow < n) h8 = *(const s8v*)&A[(long long)grow * KPAD + k0 + kq * 8];
                *(s8v*)&Xh[row * LDS_S + kq * 8] = h8;
            }
        } else {
            const float* A = (const float*)Av;
            int kq = t & 7, rbase = t >> 3;
#pragma unroll
            for (int rr = 0; rr < 4; ++rr) {
                int row = rr * 32 + rbase;
                int grow = row0 + row;
                int k = k0 + kq * 4;
                float v0 = 0.f, v1 = 0.f, v2 = 0.f, v3 = 0.f;
                if (grow < n) {
                    if (k + 4 <= K) {
                        float4 v = *(const float4*)&A[(long long)grow * K + k];
                        v0 = v.x; v1 = v.y; v2 = v.z; v3 = v.w;
                    } else {
                        if (k + 0 < K) v0 = A[(long long)grow * K + k + 0];
                        if (k + 1 < K) v1 = A[(long long)grow * K + k + 1];
                        if (k + 2 < K) v2 = A[(long long)grow * K + k + 2];
                        if (k + 3 < K) v3 = A[(long long)grow * K + k + 3];
                    }
                }
                s4v h4;
                h4[0] = (short)rne_bf16(v0);
                h4[1] = (short)rne_bf16(v1);
                h4[2] = (short)rne_bf16(v2);
                h4[3] = (short)rne_bf16(v3);
                *(s4v*)&Xh[row * LDS_S + kq * 4] = h4;
            }
        }
        __syncthreads();

        const s8v ah0 = *(const s8v*)&Xh[(wid * 32 + nn) * LDS_S + q * 8];
        const s8v ah1 = *(const s8v*)&Xh[(wid * 32 + 16 + nn) * LDS_S + q * 8];
#pragma unroll
        for (int ct = 0; ct < 4; ++ct) {
            const s8v bh = *(const s8v*)&Bh[(ct * 16 + nn) * LDS_S + q * 8];
            acc[0][ct] = __builtin_amdgcn_mfma_f32_16x16x32_bf16(ah0, bh, acc[0][ct], 0, 0, 0);
            acc[1][ct] = __builtin_amdgcn_mfma_f32_16x16x32_bf16(ah1, bh, acc[1][ct], 0, 0, 0);
        }
        __syncthreads();
    }

    // epilogue: C/D layout col=lane&15, row=(lane>>4)*4+r; store bf16
#pragma unroll
    for (int mt = 0; mt < 2; ++mt)
#pragma unroll
        for (int ct = 0; ct < 4; ++ct) {
            int col = ct * 16 + nn;
            if (col < OUTW) {
#pragma unroll
                for (int r = 0; r < 4; ++r) {
                    int row = row0 + wid * 32 + mt * 16 + q * 4 + r;
                    if (row < n) out[(long long)row * OUTW + col] = rne_bf16(acc[mt][ct][r]);
                }
            }
        }
}

// ---- MERGED: gemm1 (BW/MFMA-bound) || CSR-build scatter (latency/atomic-bound).
// Independent workloads on complementary resources; one kernel = true overlap.
__global__ __launch_bounds__(256) void build_gemm1(const void* ei,
                                                   const float* __restrict__ dinv,
                                                   int* __restrict__ cur,
                                                   int2* __restrict__ csr, int E,
                                                   int gemmBlocks,
                                                   const float* __restrict__ x,
                                                   const unsigned short* __restrict__ Wt1,
                                                   unsigned short* __restrict__ h1, int n) {
    __shared__ unsigned short Xh[128 * LDS_S];
    __shared__ unsigned short Bh[64 * LDS_S];
    if ((int)blockIdx.x < gemmBlocks) {
        gemm_tile<512, false, 64>(x, Wt1, h1, n, NN_F, blockIdx.x, Xh, Bh);
        return;
    }
    int b = (int)blockIdx.x - gemmBlocks;
    int is64 = detect_is64_block(ei, E);
    long long e = (long long)b * 256 + threadIdx.x;
    if (e >= E) return;
    int s = load_edge(ei, e, is64);
    int d = load_edge(ei, (long long)E + e, is64);
    int pos = atomicAdd(&cur[d], 1);
    csr[pos] = make_int2(s, (int)__float_as_uint(dinv[s] * dinv[d]));
}

// ---- gemm2: h2[n x 40](bf16, packed stride 40) = relu1[n x 64](bf16) @ Wt2^T ----
__global__ __launch_bounds__(256) void gemm2_kernel(const unsigned short* __restrict__ relu1,
                                                    const unsigned short* __restrict__ Wt2,
                                                    unsigned short* __restrict__ h2, int n) {
    __shared__ unsigned short Xh[128 * LDS_S];
    __shared__ unsigned short Bh[64 * LDS_S];
    gemm_tile<64, true, 40>(relu1, Wt2, h2, n, HID, blockIdx.x, Xh, Bh);
}

#define FMA8(W, H)                                          \
    acc[0] = fmaf(W, bf16_lo((H).x), acc[0]);               \
    acc[1] = fmaf(W, bf16_hi((H).x), acc[1]);               \
    acc[2] = fmaf(W, bf16_lo((H).y), acc[2]);               \
    acc[3] = fmaf(W, bf16_hi((H).y), acc[3]);               \
    acc[4] = fmaf(W, bf16_lo((H).z), acc[4]);               \
    acc[5] = fmaf(W, bf16_hi((H).z), acc[5]);               \
    acc[6] = fmaf(W, bf16_lo((H).w), acc[6]);               \
    acc[7] = fmaf(W, bf16_hi((H).w), acc[7])

// Layer-1 gather: wave per node, 8 edge slots x 8-feature octets (16B uint4 rows).
// Output written directly as bf16 (identical numerics: gemm2 staging did this rne).
__global__ __launch_bounds__(256) void gather_l1(const int2* __restrict__ csr,
                                                 const int* __restrict__ off,
                                                 const unsigned short* __restrict__ h,
                                                 const float* __restrict__ dinv,
                                                 const float* __restrict__ b,
                                                 unsigned short* __restrict__ relu1, int n) {
    const int lane = threadIdx.x & 63;
    const int g = lane >> 3, fl = lane & 7;
    const int node = __builtin_amdgcn_readfirstlane(blockIdx.x * 4 + (threadIdx.x >> 6));
    if (node >= n) return;
    const int start = off[node], end = off[node + 1];
    float acc[8];
#pragma unroll
    for (int k = 0; k < 8; ++k) acc[k] = 0.f;
    int j = start;
    for (; j + 16 <= end; j += 16) {
        int2 ea = csr[j + g];
        int2 eb = csr[j + 8 + g];
        uint4 ha = *(const uint4*)(h + (long long)ea.x * 64 + fl * 8);
        uint4 hb = *(const uint4*)(h + (long long)eb.x * 64 + fl * 8);
        float wa = __uint_as_float((unsigned)ea.y);
        float wb = __uint_as_float((unsigned)eb.y);
        FMA8(wa, ha);
        FMA8(wb, hb);
    }
    for (; j < end; j += 8) {
        int jj = j + g;
        int2 e = csr[jj < end ? jj : end - 1];
        float w = (jj < end) ? __uint_as_float((unsigned)e.y) : 0.f;
        uint4 hv = *(const uint4*)(h + (long long)e.x * 64 + fl * 8);
        FMA8(w, hv);
    }
#pragma unroll
    for (int k = 0; k < 8; ++k) {
        acc[k] += __shfl_xor(acc[k], 8);
        acc[k] += __shfl_xor(acc[k], 16);
        acc[k] += __shfl_xor(acc[k], 32);
    }
    if (g == 0) {
        // self-loop + bias + relu; lane fl owns features fl*8..fl*8+7
        float dv = dinv[node];
        float w = dv * dv;
        uint4 hn = *(const uint4*)(h + (long long)node * 64 + fl * 8);
        FMA8(w, hn);
        float4 b4a = ((const float4*)b)[fl * 2];
        float4 b4b = ((const float4*)b)[fl * 2 + 1];
        float o[8];
        o[0] = acc[0] + b4a.x; o[1] = acc[1] + b4a.y;
        o[2] = acc[2] + b4a.z; o[3] = acc[3] + b4a.w;
        o[4] = acc[4] + b4b.x; o[5] = acc[5] + b4b.y;
        o[6] = acc[6] + b4b.z; o[7] = acc[7] + b4b.w;
        s8v r;
#pragma unroll
        for (int k = 0; k < 8; ++k)
            r[k] = (short)rne_bf16(o[k] > 0.f ? o[k] : 0.f);
        *(s8v*)&relu1[(long long)node * 64 + fl * 8] = r;
    }
}

// Layer-2 gather over PACKED h2 (stride 40 shorts = 80 B, rows 16B-aligned since
// 80 = 5*16). Only lanes fl<5 load. Fused bias + relu + log_softmax.
__global__ __launch_bounds__(256) void gather_l2(const int2* __restrict__ csr,
                                                 const int* __restrict__ off,
                                                 const unsigned short* __restrict__ h,
                                                 const float* __restrict__ dinv,
                                                 const float* __restrict__ b,
                                                 float* __restrict__ out, int n) {
    const int lane = threadIdx.x & 63;
    const int g = lane >> 3, fl = lane & 7;
    const int node = __builtin_amdgcn_readfirstlane(blockIdx.x * 4 + (threadIdx.x >> 6));
    if (node >= n) return;
    const int start = off[node], end = off[node + 1];
    float acc[8];
#pragma unroll
    for (int k = 0; k < 8; ++k) acc[k] = 0.f;
    int j = start;
    for (; j + 16 <= end; j += 16) {
        int2 ea = csr[j + g];
        int2 eb = csr[j + 8 + g];
        if (fl < 5) {
            uint4 ha = *(const uint4*)(h + (long long)ea.x * 40 + fl * 8);
            uint4 hb = *(const uint4*)(h + (long long)eb.x * 40 + fl * 8);
            float wa = __uint_as_float((unsigned)ea.y);
            float wb = __uint_as_float((unsigned)eb.y);
            FMA8(wa, ha);
            FMA8(wb, hb);
        }
    }
    for (; j < end; j += 8) {
        int jj = j + g;
        int2 e = csr[jj < end ? jj : end - 1];
        if (fl < 5) {
            float w = (jj < end) ? __uint_as_float((unsigned)e.y) : 0.f;
            uint4 hv = *(const uint4*)(h + (long long)e.x * 40 + fl * 8);
            FMA8(w, hv);
        }
    }
#pragma unroll
    for (int k = 0; k < 8; ++k) {
        acc[k] += __shfl_xor(acc[k], 8);
        acc[k] += __shfl_xor(acc[k], 16);
        acc[k] += __shfl_xor(acc[k], 32);
    }
    // self-loop + bias + relu on fl<5 lanes (redundant across g), 8-lane softmax
    float v[8];
    float vmax = -1e30f;
    if (fl < 5) {
        float dv = dinv[node];
        float w = dv * dv;
        uint4 hn = *(const uint4*)(h + (long long)node * 40 + fl * 8);
        FMA8(w, hn);
        float4 b4a = ((const float4*)b)[fl * 2];
        float4 b4b = ((const float4*)b)[fl * 2 + 1];
        v[0] = acc[0] + b4a.x; v[1] = acc[1] + b4a.y;
        v[2] = acc[2] + b4a.z; v[3] = acc[3] + b4a.w;
        v[4] = acc[4] + b4b.x; v[5] = acc[5] + b4b.y;
        v[6] = acc[6] + b4b.z; v[7] = acc[7] + b4b.w;
#pragma unroll
        for (int k = 0; k < 8; ++k) {
            v[k] = v[k] > 0.f ? v[k] : 0.f;
            vmax = fmaxf(vmax, v[k]);
        }
    }
#pragma unroll
    for (int o = 1; o < 8; o <<= 1) vmax = fmaxf(vmax, __shfl_xor(vmax, o));
    float ssum = 0.f;
    if (fl < 5) {
#pragma unroll
        for (int k = 0; k < 8; ++k) ssum += expf(v[k] - vmax);
    }
#pragma unroll
    for (int o = 1; o < 8; o <<= 1) ssum += __shfl_xor(ssum, o);
    if (g == 0 && fl < 5) {
        float ls = vmax + logf(ssum);
        float4 o0 = make_float4(v[0] - ls, v[1] - ls, v[2] - ls, v[3] - ls);
        float4 o1 = make_float4(v[4] - ls, v[5] - ls, v[6] - ls, v[7] - ls);
        float4* dst = (float4*)(out + (long long)node * NC + fl * 8);
        dst[0] = o0;
        dst[1] = o1;
    }
}

static inline char* align256(char* p) {
    return (char*)(((uintptr_t)p + 255) & ~(uintptr_t)255);
}

extern "C" void kernel_launch(void* const* d_in, const int* in_sizes, int n_in,
                              void* d_out, int out_size, void* d_ws, size_t ws_size,
                              hipStream_t stream) {
    const float* x  = (const float*)d_in[0];
    const void*  ei = d_in[1];
    const float* W1 = (const float*)d_in[2];
    const float* b1 = (const float*)d_in[3];
    const float* W2 = (const float*)d_in[4];
    const float* b2 = (const float*)d_in[5];
    float* out = (float*)d_out;
    const int n = in_sizes[0] / NN_F;   // 100000
    const int E = in_sizes[1] / 2;      // 1600000
    const int nScanBlocks = (n + SCAN_B - 1) / SCAN_B;
    const int degBlocks = (E + 255) / 256;
    const int gemmBlocks = (n + 127) / 128;

    char* p = (char*)d_ws;
    int* deg  = (int*)p;                 p = align256(p + (size_t)n * sizeof(int));
    int* off  = (int*)p;                 p = align256(p + (size_t)(n + 1) * sizeof(int));
    int* cur  = (int*)p;                 p = align256(p + (size_t)n * sizeof(int));
    int* bsums = (int*)p;                p = align256(p + 256 * sizeof(int));
    float* dinv = (float*)p;             p = align256(p + (size_t)n * sizeof(float));
    int2* csr = (int2*)p;                p = align256(p + (size_t)E * sizeof(int2));
    unsigned short* Wt1 = (unsigned short*)p; p = align256(p + (size_t)64 * 512 * sizeof(short));
    unsigned short* Wt2 = (unsigned short*)p; p = align256(p + (size_t)64 * 64 * sizeof(short));
    unsigned short* h1 = (unsigned short*)p; p = align256(p + (size_t)n * 64 * sizeof(unsigned short));
    unsigned short* relu1 = (unsigned short*)p; p = align256(p + (size_t)n * 64 * sizeof(unsigned short));
    unsigned short* h2 = h1;  // reuse: h1 dead after gather_l1 (h2 is n*40 <= n*64)

    (void)hipMemsetAsync(deg, 0, (size_t)n * sizeof(int), stream);
    deg_wprep<<<degBlocks + 144, 256, 0, stream>>>(ei, deg, W1, W2, Wt1, Wt2, E, degBlocks);

    scan1<<<nScanBlocks, SCAN_T, 0, stream>>>(deg, off, bsums, dinv, n);
    if (nScanBlocks <= 64) {
        scan_fin<<<nScanBlocks, SCAN_T, 0, stream>>>(off, cur, bsums, n, nScanBlocks);
    } else {
        scan2<<<1, 64, 0, stream>>>(bsums, off, nScanBlocks, n);
        scan3<<<nScanBlocks, SCAN_T, 0, stream>>>(off, cur, bsums, n);
    }

    // gemm1 (BW-bound) and CSR build (latency-bound) overlap in one dispatch
    build_gemm1<<<gemmBlocks + degBlocks, 256, 0, stream>>>(ei, dinv, cur, csr, E,
                                                            gemmBlocks, x, Wt1, h1, n);

    gather_l1<<<(n + 3) / 4, 256, 0, stream>>>(csr, off, h1, dinv, b1, relu1, n);
    gemm2_kernel<<<gemmBlocks, 256, 0, stream>>>(relu1, Wt2, h2, n);
    gather_l2<<<(n + 3) / 4, 256, 0, stream>>>(csr, off, h2, dinv, b2, out, n);
}